// Round 5
// baseline (1192.842 us; speedup 1.0000x reference)
//
#include <hip/hip_runtime.h>

#define NN 12288
#define OUTF 64
#define ALPHA 0.2f
#define C1 6.0f

typedef unsigned short u16;
typedef unsigned int u32;
typedef unsigned long long u64;
typedef _Float16 half8 __attribute__((ext_vector_type(8)));
typedef float floatx4 __attribute__((ext_vector_type(4)));
typedef int intx4 __attribute__((ext_vector_type(4)));

union H16 { u16 u; _Float16 h; };
__device__ __forceinline__ u16 f2h(float f) { H16 c; c.h = (_Float16)f; return c.u; }

// ---------------- K1: h = X@W, per-node scalars, Btf in MFMA-fragment order --------------
// Btf chunk index (k32, n, lane): 16 B = 8 fp16, element j' = B_row(n*16+lane%16) at
// source node k32*32 + (lane/16)*8 + j'.  B_row r: r<64: e1*h[r]; r==64: e1; 65..79: 0;
// 80..143: e2*h[r-80]; r==144: e2; 145..159: 0.   e1=exp(s2-C1), e2=exp(a*s2).
__global__ __launch_bounds__(256) void k1_prep(
    const float* __restrict__ inp, const float* __restrict__ W, const float* __restrict__ a,
    u16* __restrict__ e1h, u16* __restrict__ thh,
    float* __restrict__ f1g, float* __restrict__ f2g, u16* __restrict__ Btf)
{
  __shared__ float Wl[128 * 64];
  __shared__ float hsm[16][66];
  __shared__ float e1sm[16], e2sm[16];
  const int tid = threadIdx.x;
  for (int t = tid; t < 128 * 64 / 4; t += 256)
    ((float4*)Wl)[t] = ((const float4*)W)[t];
  const int wave = tid >> 6, lane = tid & 63;
  const int k16 = blockIdx.x;                  // 16-node group
  const float a1l = a[lane], a2l = a[OUTF + lane];
  __syncthreads();
  for (int jl = 0; jl < 4; ++jl) {
    const int jn = wave * 4 + jl;              // local node 0..15
    const int j = k16 * 16 + jn;
    const float4* xp = (const float4*)(inp + (size_t)j * 128);
    float h = 0.f;
#pragma unroll
    for (int c4 = 0; c4 < 32; ++c4) {
      float4 v = xp[c4];
      const int k = c4 * 4;
      h += v.x * Wl[k * 64 + lane] + v.y * Wl[(k + 1) * 64 + lane]
         + v.z * Wl[(k + 2) * 64 + lane] + v.w * Wl[(k + 3) * 64 + lane];
    }
    float p1 = h * a1l, p2 = h * a2l;
#pragma unroll
    for (int off = 32; off > 0; off >>= 1) { p1 += __shfl_xor(p1, off); p2 += __shfl_xor(p2, off); }
    hsm[jn][lane] = h;
    if (lane == 0) {
      const float s1 = p1, s2 = p2;
      const float e1 = expf(s2 - C1), e2 = expf(ALPHA * s2);
      e1sm[jn] = e1; e2sm[jn] = e2;
      e1h[j] = f2h(e1);
      thh[j] = f2h(expf(-s1 - C1));            // pos branch iff e1h[j] > thh[i] (u16-monotone)
      f1g[j] = expf(s1 + C1);
      f2g[j] = expf(ALPHA * s1);
    }
  }
  __syncthreads();
  // phase B: this block covers half a k32 slab: lanes [hi, hi+32) of every n-chunk
  const int k32 = k16 >> 1, hi = (k16 & 1) * 32;
  for (int cc = tid; cc < 320; cc += 256) {
    const int n = cc >> 5, l32 = cc & 31;
    const int r = n * 16 + (l32 & 15);
    const int jb = (l32 >> 4) * 8;             // local node base for this lane's 8 elements
    u32 wpk[4];
#pragma unroll
    for (int p = 0; p < 4; ++p) {
      u16 hh[2];
#pragma unroll
      for (int q2 = 0; q2 < 2; ++q2) {
        const int jj = jb + p * 2 + q2;
        float v;
        if (r < 64)        v = e1sm[jj] * hsm[jj][r];
        else if (r == 64)  v = e1sm[jj];
        else if (r < 80)   v = 0.f;
        else if (r < 144)  v = e2sm[jj] * hsm[jj][r - 80];
        else if (r == 144) v = e2sm[jj];
        else               v = 0.f;
        hh[q2] = f2h(v);
      }
      wpk[p] = (u32)hh[0] | ((u32)hh[1] << 16);
    }
    ((uint4*)Btf)[(size_t)(k32 * 10 + n) * 64 + hi + l32] = make_uint4(wpk[0], wpk[1], wpk[2], wpk[3]);
  }
}

// ---------------- K_PACK: stream adj once (coalesced), emit branch-resolved bit masks ----
// P1[i] bit j = adj[i][j]!=0 && e1h[j] > thh[i];  P2 = adj && !up.  1 block per row.
__global__ __launch_bounds__(256) void k_pack(
    const int* __restrict__ adj, const u16* __restrict__ e1h, const u16* __restrict__ thh,
    unsigned char* __restrict__ P1, unsigned char* __restrict__ P2)
{
  const int i = blockIdx.x, tid = threadIdx.x;
  const u16 th = thh[i];
  const int* arow = adj + (size_t)i * NN;
  unsigned char* p1r = P1 + (size_t)i * (NN / 8);
  unsigned char* p2r = P2 + (size_t)i * (NN / 8);
#pragma unroll
  for (int it = 0; it < NN / 2048; ++it) {
    const int cb = it * 2048 + tid * 8;
    intx4 a0 = *reinterpret_cast<const intx4*>(arow + cb);
    intx4 a1 = *reinterpret_cast<const intx4*>(arow + cb + 4);
    uint4 ev = *reinterpret_cast<const uint4*>(e1h + cb);
    const int av[8] = {a0.x, a0.y, a0.z, a0.w, a1.x, a1.y, a1.z, a1.w};
    const u32 ew[4] = {ev.x, ev.y, ev.z, ev.w};
    u32 b1 = 0, b2 = 0;
#pragma unroll
    for (int e = 0; e < 8; ++e) {
      const u16 eh = (u16)(ew[e >> 1] >> ((e & 1) * 16));
      const bool bit = av[e] != 0;
      const bool up = eh > th;                 // positive fp16 compares as u16
      b1 |= (u32)(bit && up) << e;
      b2 |= (u32)(bit && !up) << e;
    }
    p1r[it * 256 + tid] = (unsigned char)b1;   // lanes' bytes contiguous -> coalesced
    p2r[it * 256 + tid] = (unsigned char)b2;
  }
}

// ---------------- K2: bit-masked dual GEMM, coalesced fragment loads ---------------------
// 768 blocks x 16 rows; wave w = K-chunk w; in-LDS split-K reduce + fused epilogue.
__global__ __launch_bounds__(256, 3) void k2_main(
    const unsigned char* __restrict__ P1, const unsigned char* __restrict__ P2,
    const u16* __restrict__ Btf, const float* __restrict__ f1g, const float* __restrict__ f2g,
    float* __restrict__ out)
{
  __shared__ float red[4][16][132];
  __shared__ float dred[4][16][2];
  const int tid = threadIdx.x;
  const int wave = tid >> 6, lane = tid & 63;
  const int quad = lane >> 4, lr = lane & 15;
  const int mbase = (int)blockIdx.x * 16;
  const int ia = mbase + lr;
  const u64* b1row = reinterpret_cast<const u64*>(P1 + (size_t)ia * (NN / 8));
  const u64* b2row = reinterpret_cast<const u64*>(P2 + (size_t)ia * (NN / 8));
  const int k0 = wave * (NN / 4);

  floatx4 acc[10];
#pragma unroll
  for (int n = 0; n < 10; ++n) acc[n] = (floatx4){0.f, 0.f, 0.f, 0.f};

  for (int kb = k0; kb < k0 + NN / 4; kb += 64) {
    const u64 b1 = b1row[kb >> 6];
    const u64 b2 = b2row[kb >> 6];
#pragma unroll
    for (int h = 0; h < 2; ++h) {
      const int k32 = (kb >> 5) + h;
      const u32 sh = (u32)(h * 32 + quad * 8);
      const u32 m1 = (u32)(b1 >> sh) & 0xFFu;
      const u32 m2 = (u32)(b2 >> sh) & 0xFFu;
      union { half8 v; u16 s[8]; } A1, A2;
#pragma unroll
      for (int e = 0; e < 8; ++e) {
        A1.s[e] = ((m1 >> e) & 1u) ? (u16)0x3C00 : (u16)0;
        A2.s[e] = ((m2 >> e) & 1u) ? (u16)0x3C00 : (u16)0;
      }
      const half8* bp = reinterpret_cast<const half8*>(Btf + ((size_t)k32 * 10 * 64 + lane) * 8);
#pragma unroll
      for (int n = 0; n < 10; ++n) {
        half8 Bv = bp[n * 64];                 // 64 lanes x 16 B contiguous (1 KB burst)
        acc[n] = __builtin_amdgcn_mfma_f32_16x16x32_f16(n < 5 ? A1.v : A2.v, Bv, acc[n], 0, 0, 0);
      }
    }
  }

  // C/D: col=lane&15 (feature within group), row=quad*4+reg
#pragma unroll
  for (int n = 0; n < 4; ++n)
#pragma unroll
    for (int r = 0; r < 4; ++r)
      red[wave][quad * 4 + r][n * 16 + lr] = acc[n][r];
#pragma unroll
  for (int n = 5; n < 9; ++n)
#pragma unroll
    for (int r = 0; r < 4; ++r)
      red[wave][quad * 4 + r][64 + (n - 5) * 16 + lr] = acc[n][r];
  if (lr == 0) {
#pragma unroll
    for (int r = 0; r < 4; ++r) {
      dred[wave][quad * 4 + r][0] = acc[4][r]; // den+ lives in group 4, feature-col 0
      dred[wave][quad * 4 + r][1] = acc[9][r]; // den- in group 9, col 0
    }
  }
  __syncthreads();

#pragma unroll
  for (int it = 0; it < 4; ++it) {
    const int idx = tid + it * 256;
    const int row = idx >> 6, col = idx & 63;
    float n1 = 0.f, n2 = 0.f, d1 = 0.f, d2 = 0.f;
#pragma unroll
    for (int w = 0; w < 4; ++w) {
      n1 += red[w][row][col];
      n2 += red[w][row][64 + col];
      d1 += dred[w][row][0];
      d2 += dred[w][row][1];
    }
    const float f1 = f1g[mbase + row], f2 = f2g[mbase + row];
    const float num = f1 * n1 + f2 * n2;
    const float den = fmaxf(f1 * d1 + f2 * d2, 1e-30f);
    const float x = num / den;
    out[(size_t)(mbase + row) * OUTF + col] = x > 0.f ? x : (expf(x) - 1.f);
  }
}

extern "C" void kernel_launch(void* const* d_in, const int* in_sizes, int n_in,
                              void* d_out, int out_size, void* d_ws, size_t ws_size,
                              hipStream_t stream) {
  const float* inp = (const float*)d_in[0];
  const int* adj = (const int*)d_in[1];
  const float* W = (const float*)d_in[2];
  const float* a = (const float*)d_in[3];

  // ws: Btf 3,932,160 | P1 18,874,368 | P2 18,874,368 | e1h 24,576 | thh 24,576
  //     f1g 49,152 | f2g 49,152   (total ~41.8 MB)
  char* ws = (char*)d_ws;
  u16* Btf = (u16*)ws;
  unsigned char* P1 = (unsigned char*)(ws + 3932160);
  unsigned char* P2 = P1 + 18874368;
  u16* e1h = (u16*)(ws + 3932160 + 2 * 18874368);
  u16* thh = e1h + NN;
  float* f1g = (float*)(thh + NN);
  float* f2g = f1g + NN;

  k1_prep<<<768, 256, 0, stream>>>(inp, W, a, e1h, thh, f1g, f2g, Btf);
  k_pack<<<NN, 256, 0, stream>>>(adj, e1h, thh, P1, P2);
  k2_main<<<768, 256, 0, stream>>>(P1, P2, Btf, f1g, f2g, (float*)d_out);
}